// Round 2
// baseline (440.247 us; speedup 1.0000x reference)
//
#include <hip/hip_runtime.h>
#include <hip/hip_bf16.h>
#include <stdint.h>
#include <stddef.h>

typedef unsigned short ushortT;
typedef __attribute__((ext_vector_type(8))) short bf16x8s;  // 8 bf16 bits in 4 VGPRs
typedef __attribute__((ext_vector_type(4))) float f32x4;

// ---------------------------------------------------------------- helpers ---

__device__ __forceinline__ short f2bf(float f) {
  unsigned u = __float_as_uint(f);
  u += 0x7FFFu + ((u >> 16) & 1u);     // RNE; inputs finite so no NaN guard
  return (short)(u >> 16);
}
__device__ __forceinline__ float bf2f(ushortT s) {
  return __uint_as_float(((unsigned)s) << 16);
}

// Load 8 contiguous bf16 values (as bits) starting at element offset `off`,
// from a buffer that is fp32 (isf32=1) or bf16 (isf32=0).
__device__ __forceinline__ bf16x8s load_a8(const void* A, int isf32, size_t off) {
  if (isf32) {
    const float4* p = (const float4*)((const float*)A + off);
    float4 x = p[0], y = p[1];
    bf16x8s r;
    r[0] = f2bf(x.x); r[1] = f2bf(x.y); r[2] = f2bf(x.z); r[3] = f2bf(x.w);
    r[4] = f2bf(y.x); r[5] = f2bf(y.y); r[6] = f2bf(y.z); r[7] = f2bf(y.w);
    return r;
  }
  return *(const bf16x8s*)((const ushortT*)A + off);
}

// ------------------------------------------------------------ dtype probe ---
// fp32 N(0,1) data viewed as f32: |x| in [1e-8,1e8] ~always.
// bf16-packed data viewed as f32: exponent field is garbage (~2^113+ or tiny).
__global__ void detect_dtype(const unsigned* __restrict__ q, int* __restrict__ flag) {
  __shared__ int cnt;
  if (threadIdx.x == 0) cnt = 0;
  __syncthreads();
  int c = 0;
  for (int i = threadIdx.x; i < 4096; i += 256) {
    float a = fabsf(__uint_as_float(q[i]));
    if (a > 1e-8f && a < 1e8f) c++;
  }
  atomicAdd(&cnt, c);
  __syncthreads();
  if (threadIdx.x == 0) *flag = (cnt > 2048) ? 1 : 0;
}

// ------------------------------------------------------------- transpose ---
// Wt[z][n*1024+k] = W[z][k*1024+n]  (bf16 bits out), dual-dtype in.
__global__ void transpose_w(const void* __restrict__ Wq, const void* __restrict__ Wk,
                            const void* __restrict__ Wv, const void* __restrict__ Wo,
                            const int* __restrict__ flag, ushortT* __restrict__ Wt)
{
  __shared__ __align__(16) ushortT t[32][33];
  const int isf32 = *flag;
  const int z = blockIdx.z;
  const void* W = (z == 0) ? Wq : (z == 1) ? Wk : (z == 2) ? Wv : Wo;
  ushortT* dst = Wt + (size_t)z * 1024 * 1024;
  const int x = blockIdx.x * 32, y = blockIdx.y * 32;
  const int tx = threadIdx.x, ty = threadIdx.y;
#pragma unroll
  for (int i = ty; i < 32; i += 8) {
    const size_t idx = (size_t)(y + i) * 1024 + x + tx;
    t[i][tx] = isf32 ? (ushortT)f2bf(((const float*)W)[idx])
                     : ((const ushortT*)W)[idx];
  }
  __syncthreads();
#pragma unroll
  for (int i = ty; i < 32; i += 8)
    dst[(size_t)(x + i) * 1024 + y + tx] = t[tx][i];
}

// --------------------------------------------------------------- GEMM core --
// C = A[M,K] * Bt[N,K]^T, fp32 accum. 256 thr = 4 waves 2x2, wave = 64x64.
// Conservative staging: global->regs->ds_write_b128 (no global_load_lds).
__device__ __forceinline__ void gemm_core_128(
    const void* __restrict__ A, int a_isf32, const ushortT* __restrict__ Bt,
    int K, ushortT* As, ushortT* Bs, f32x4 (&acc)[4][4], int m0, int n0)
{
  const int tid  = threadIdx.x;
  const int wave = tid >> 6, lane = tid & 63;
  const int wm = (wave & 1) << 6;
  const int wn = (wave >> 1) << 6;
  const int lr = lane & 15;
  const int lk = (lane >> 4) << 3;

#pragma unroll
  for (int mi = 0; mi < 4; ++mi)
#pragma unroll
    for (int ni = 0; ni < 4; ++ni)
      acc[mi][ni] = (f32x4){0.f, 0.f, 0.f, 0.f};

  for (int k0 = 0; k0 < K; k0 += 32) {
    bf16x8s av[2], bv[2];
#pragma unroll
    for (int i = 0; i < 2; ++i) {
      const int cc  = tid + (i << 8);       // chunk 0..511 (16B each)
      const int row = cc >> 2;              // 4 chunks per 32-elem row
      const int ko  = (cc & 3) << 3;
      av[i] = load_a8(A, a_isf32, (size_t)(m0 + row) * K + k0 + ko);
      bv[i] = *(const bf16x8s*)(Bt + (size_t)(n0 + row) * K + k0 + ko);
    }
    __syncthreads();                        // prior readers done
#pragma unroll
    for (int i = 0; i < 2; ++i) {
      const int cc = tid + (i << 8);
      *(bf16x8s*)(As + cc * 8) = av[i];
      *(bf16x8s*)(Bs + cc * 8) = bv[i];
    }
    __syncthreads();                        // writes visible

    bf16x8s af[4], bfr[4];
#pragma unroll
    for (int i = 0; i < 4; ++i)
      af[i] = *(const bf16x8s*)(As + (wm + i * 16 + lr) * 32 + lk);
#pragma unroll
    for (int i = 0; i < 4; ++i)
      bfr[i] = *(const bf16x8s*)(Bs + (wn + i * 16 + lr) * 32 + lk);

#pragma unroll
    for (int mi = 0; mi < 4; ++mi)
#pragma unroll
      for (int ni = 0; ni < 4; ++ni)
        acc[mi][ni] = __builtin_amdgcn_mfma_f32_16x16x32_bf16(
            af[mi], bfr[ni], acc[mi][ni], 0, 0, 0);
  }
}

// ------------------------------------------------------ projection GEMMs ---
// z=0: Q -> Qh[B,H,L,64]; z=1: K -> Kh[B,H,L,64]; z=2: V -> Vt[B,H,64,L]
__global__ __launch_bounds__(256)
void proj_gemm(const void* __restrict__ q, const void* __restrict__ k,
               const void* __restrict__ v, const ushortT* __restrict__ WtAll,
               const void* __restrict__ bq, const void* __restrict__ bk,
               const void* __restrict__ bv, const int* __restrict__ flag,
               ushortT* __restrict__ Qh, ushortT* __restrict__ Kh,
               ushortT* __restrict__ Vt)
{
  __shared__ __align__(16) ushortT As[128 * 32];
  __shared__ __align__(16) ushortT Bs[128 * 32];
  const int isf32 = *flag;
  const int which = blockIdx.z;
  const void* A     = (which == 0) ? q  : (which == 1) ? k  : v;
  const ushortT* Bt = WtAll + (size_t)which * 1024 * 1024;
  const void* bias  = (which == 0) ? bq : (which == 1) ? bk : bv;
  const int m0 = blockIdx.x * 128, n0 = blockIdx.y * 128;

  f32x4 acc[4][4];
  gemm_core_128(A, isf32, Bt, 1024, As, Bs, acc, m0, n0);

  const int lane = threadIdx.x & 63, wave = threadIdx.x >> 6;
  const int wm = (wave & 1) << 6, wn = (wave >> 1) << 6;
  const int lr = lane & 15, quad = lane >> 4;

#pragma unroll
  for (int ni = 0; ni < 4; ++ni) {
    const int n = n0 + wn + ni * 16 + lr;
    const float bias_v = isf32 ? ((const float*)bias)[n]
                               : bf2f(((const ushortT*)bias)[n]);
    const int h = n >> 6, d = n & 63;
#pragma unroll
    for (int mi = 0; mi < 4; ++mi) {
#pragma unroll
      for (int r = 0; r < 4; ++r) {
        const int m = m0 + wm + mi * 16 + quad * 4 + r;
        const int b = m >> 11, l = m & 2047;
        const ushortT o = (ushortT)f2bf(acc[mi][ni][r] + bias_v);
        const size_t bh = (size_t)(b * 16 + h);
        if (which == 0)      Qh[(bh * 2048 + l) * 64 + d] = o;
        else if (which == 1) Kh[(bh * 2048 + l) * 64 + d] = o;
        else                 Vt[(bh * 64 + d) * 2048 + l] = o;
      }
    }
  }
}

// ------------------------------------------------------- flash attention ---
// grid (32,16,2): x = 64-row Q tile, y = head, z = batch. 4 waves/block,
// each wave owns 16 Q rows, streams 32-key tiles. All-internal bf16.
__global__ __launch_bounds__(256)
void attn_kernel(const ushortT* __restrict__ Qh, const ushortT* __restrict__ Kh,
                 const ushortT* __restrict__ Vt, ushortT* __restrict__ Ob)
{
  const int b = blockIdx.z, h = blockIdx.y, qt = blockIdx.x;
  const int bh = b * 16 + h;
  const int wave = threadIdx.x >> 6, lane = threadIdx.x & 63;
  const int lr = lane & 15, quad = lane >> 4, lk = quad * 8;
  const int q0 = qt * 64 + wave * 16;

  const ushortT* Q = Qh + ((size_t)bh * 2048 + q0) * 64;
  const ushortT* K = Kh + (size_t)bh * 2048 * 64;
  const ushortT* V = Vt + (size_t)bh * 64 * 2048;

  __shared__ __align__(16) ushortT Pls[4][16 * 32];  // per-wave P tile
  ushortT* P = Pls[wave];

  const bf16x8s qf0 = *(const bf16x8s*)(Q + lr * 64 + lk);
  const bf16x8s qf1 = *(const bf16x8s*)(Q + lr * 64 + 32 + lk);

  f32x4 o[4];
#pragma unroll
  for (int i = 0; i < 4; ++i) o[i] = (f32x4){0.f, 0.f, 0.f, 0.f};
  float mrow[4] = {-1e30f, -1e30f, -1e30f, -1e30f};
  float lsum[4] = {0.f, 0.f, 0.f, 0.f};
  const float cexp = 0.18033688011112042f;  // log2(e) / sqrt(Dk=64)

  for (int kt = 0; kt < 2048; kt += 32) {
    f32x4 s0 = (f32x4){0.f, 0.f, 0.f, 0.f};
    f32x4 s1 = (f32x4){0.f, 0.f, 0.f, 0.f};
    {
      const ushortT* Kb0 = K + (size_t)(kt + lr) * 64 + lk;
      const bf16x8s ka = *(const bf16x8s*)(Kb0);
      const bf16x8s kb = *(const bf16x8s*)(Kb0 + 32);
      s0 = __builtin_amdgcn_mfma_f32_16x16x32_bf16(qf0, ka, s0, 0, 0, 0);
      s0 = __builtin_amdgcn_mfma_f32_16x16x32_bf16(qf1, kb, s0, 0, 0, 0);
      const ushortT* Kb1 = K + (size_t)(kt + 16 + lr) * 64 + lk;
      const bf16x8s kc = *(const bf16x8s*)(Kb1);
      const bf16x8s kd = *(const bf16x8s*)(Kb1 + 32);
      s1 = __builtin_amdgcn_mfma_f32_16x16x32_bf16(qf0, kc, s1, 0, 0, 0);
      s1 = __builtin_amdgcn_mfma_f32_16x16x32_bf16(qf1, kd, s1, 0, 0, 0);
    }

    float alpha[4];
#pragma unroll
    for (int r = 0; r < 4; ++r) {
      float mx = fmaxf(s0[r], s1[r]);
      mx = fmaxf(mx, __shfl_xor(mx, 1));
      mx = fmaxf(mx, __shfl_xor(mx, 2));
      mx = fmaxf(mx, __shfl_xor(mx, 4));
      mx = fmaxf(mx, __shfl_xor(mx, 8));
      const float mnew = fmaxf(mrow[r], mx);
      alpha[r] = exp2f((mrow[r] - mnew) * cexp);
      mrow[r] = mnew;
      const float p0 = exp2f((s0[r] - mnew) * cexp);
      const float p1 = exp2f((s1[r] - mnew) * cexp);
      float sum = p0 + p1;
      sum += __shfl_xor(sum, 1);
      sum += __shfl_xor(sum, 2);
      sum += __shfl_xor(sum, 4);
      sum += __shfl_xor(sum, 8);
      lsum[r] = lsum[r] * alpha[r] + sum;
      const int row = quad * 4 + r;
      P[row * 32 + lr]      = (ushortT)f2bf(p0);
      P[row * 32 + 16 + lr] = (ushortT)f2bf(p1);
    }
    __syncthreads();  // conservative: make P writes visible (uniform trip count)
    const bf16x8s pf = *(const bf16x8s*)(P + lr * 32 + lk);

#pragma unroll
    for (int nt = 0; nt < 4; ++nt) {
#pragma unroll
      for (int r = 0; r < 4; ++r) o[nt][r] *= alpha[r];
      const bf16x8s vf = *(const bf16x8s*)(V + (size_t)(nt * 16 + lr) * 2048 + kt + lk);
      o[nt] = __builtin_amdgcn_mfma_f32_16x16x32_bf16(pf, vf, o[nt], 0, 0, 0);
    }
    __syncthreads();  // P consumed before next iteration overwrites
  }

  float inv[4];
#pragma unroll
  for (int r = 0; r < 4; ++r) inv[r] = 1.0f / lsum[r];
#pragma unroll
  for (int nt = 0; nt < 4; ++nt) {
    const int dcol = h * 64 + nt * 16 + lr;
#pragma unroll
    for (int r = 0; r < 4; ++r) {
      const int l = q0 + quad * 4 + r;
      Ob[((size_t)b * 2048 + l) * 1024 + dcol] = (ushortT)f2bf(o[nt][r] * inv[r]);
    }
  }
}

// ---------------------------------------------------------- output GEMM ----
__global__ __launch_bounds__(256)
void out_gemm(const ushortT* __restrict__ Ob, const ushortT* __restrict__ Wto,
              const void* __restrict__ bo, const int* __restrict__ flag,
              void* __restrict__ C)
{
  __shared__ __align__(16) ushortT As[128 * 32];
  __shared__ __align__(16) ushortT Bs[128 * 32];
  const int isf32 = *flag;
  const int m0 = blockIdx.x * 128, n0 = blockIdx.y * 128;

  f32x4 acc[4][4];
  gemm_core_128(Ob, 0, Wto, 1024, As, Bs, acc, m0, n0);

  const int lane = threadIdx.x & 63, wave = threadIdx.x >> 6;
  const int wm = (wave & 1) << 6, wn = (wave >> 1) << 6;
  const int lr = lane & 15, quad = lane >> 4;

#pragma unroll
  for (int ni = 0; ni < 4; ++ni) {
    const int n = n0 + wn + ni * 16 + lr;
    const float bias_v = isf32 ? ((const float*)bo)[n]
                               : bf2f(((const ushortT*)bo)[n]);
#pragma unroll
    for (int mi = 0; mi < 4; ++mi) {
#pragma unroll
      for (int r = 0; r < 4; ++r) {
        const int m = m0 + wm + mi * 16 + quad * 4 + r;
        const float val = acc[mi][ni][r] + bias_v;
        const size_t idx = (size_t)m * 1024 + n;
        if (isf32) ((float*)C)[idx] = val;
        else       ((ushortT*)C)[idx] = (ushortT)f2bf(val);
      }
    }
  }
}

// -------------------------------------------------------------- launcher ---
extern "C" void kernel_launch(void* const* d_in, const int* in_sizes, int n_in,
                              void* d_out, int out_size, void* d_ws, size_t ws_size,
                              hipStream_t stream) {
  const void* q  = d_in[0];
  const void* k  = d_in[1];
  const void* v  = d_in[2];
  const void* Wq = d_in[3];
  const void* bq = d_in[4];
  const void* Wk = d_in[5];
  const void* bk = d_in[6];
  const void* Wv = d_in[7];
  const void* bv = d_in[8];
  const void* Wo = d_in[9];
  const void* bo = d_in[10];

  char* ws = (char*)d_ws;
  int*     flag = (int*)ws;                          // 4 B
  ushortT* Wt = (ushortT*)(ws + (size_t)(1  << 20)); // 4x1024x1024 bf16 = 8 MB
  ushortT* Qh = (ushortT*)(ws + (size_t)(9  << 20)); // [B,H,L,64]  8 MB
  ushortT* Kh = (ushortT*)(ws + (size_t)(17 << 20)); // [B,H,L,64]  8 MB
  ushortT* Vt = (ushortT*)(ws + (size_t)(25 << 20)); // [B,H,64,L]  8 MB
  ushortT* Ob = (ushortT*)(ws + (size_t)(33 << 20)); // [B*L,1024]  8 MB

  detect_dtype<<<1, 256, 0, stream>>>((const unsigned*)q, flag);
  transpose_w<<<dim3(32, 32, 4), dim3(32, 8), 0, stream>>>(Wq, Wk, Wv, Wo, flag, Wt);
  proj_gemm<<<dim3(32, 8, 3), dim3(256), 0, stream>>>(q, k, v, Wt, bq, bk, bv,
                                                      flag, Qh, Kh, Vt);
  attn_kernel<<<dim3(32, 16, 2), dim3(256), 0, stream>>>(Qh, Kh, Vt, Ob);
  out_gemm<<<dim3(32, 8), dim3(256), 0, stream>>>(Ob, Wt + (size_t)3 * 1024 * 1024,
                                                  bo, flag, d_out);
}